// Round 8
// baseline (255.308 us; speedup 1.0000x reference)
//
#include <hip/hip_runtime.h>

typedef unsigned short u16;
typedef unsigned int u32;
typedef __attribute__((ext_vector_type(4))) float f32x4;
typedef __attribute__((ext_vector_type(16))) float f32x16;
typedef __attribute__((ext_vector_type(8))) short s16x8;
typedef __attribute__((ext_vector_type(4))) u16 u16x4;

#define L2E 1.4426950408889634f
#define QSCALE 0.18033688011112042f /* (1/8) * log2(e) */

__device__ __forceinline__ float bf2f(u16 u) {
    union { u32 i; float f; } v; v.i = ((u32)u) << 16; return v.f;
}
__device__ __forceinline__ u16 f2bf(float f) {  // RNE
    union { float f; u32 i; } v; v.f = f;
    return (u16)((v.i + 0x7fffu + ((v.i >> 16) & 1u)) >> 16);
}
// pack hi16(a) | hi16(b)<<16  (bf16 truncation)
__device__ __forceinline__ u32 pack_hi(float a, float b) {
    union { float f; u32 i; } x, y; x.f = a; y.f = b;
    return (x.i >> 16) | (y.i & 0xFFFF0000u);
}
__device__ __forceinline__ void gl2lds16(const u16* g, u16* l) {
    __builtin_amdgcn_global_load_lds(
        (const __attribute__((address_space(1))) void*)g,
        (__attribute__((address_space(3))) void*)l, 16, 0, 0);
}

// ---------------------------------------------------------------------------
// prep = conv (blocks 0..9215) + lg (blocks 9216..13311).
// lg emits LGx in the 32x32 MFMA C-layout order:
//   flat = ((((b*64+qt)*32+kt)*2+ks)*64+lane)*16 + reg
//   value = log2(sigmoid(gw*SC+gb)+1e-8) at q = qt*32+(lane&31),
//           key = kt*64 + ks*32 + (reg&3)+8*(reg>>2)+4*(lane>>5).
// ---------------------------------------------------------------------------
__global__ __launch_bounds__(256) void prep_kernel(
    const float* __restrict__ s0, const float* __restrict__ s1,
    const float* __restrict__ s2, const float* __restrict__ s3,
    const float* __restrict__ s4, const float* __restrict__ s5,
    u16* __restrict__ dst,
    const float* __restrict__ SC, const float* __restrict__ gwp,
    const float* __restrict__ gbp, u16* __restrict__ LGx)
{
    if (blockIdx.x < 9216) {
        int e = (blockIdx.x * 256 + threadIdx.x) * 4;
        const float* src; int off;
        if      (e < 4194304) { src = s0; off = e; }
        else if (e < 8388608) { src = s1; off = e - 4194304; }
        else if (e < 8650752) { src = s2; off = e - 8388608; }
        else if (e < 8912896) { src = s3; off = e - 8650752; }
        else if (e < 9175040) { src = s4; off = e - 8912896; }
        else                  { src = s5; off = e - 9175040; }
        f32x4 f = *(const f32x4*)(src + off);
        u16x4 o;
#pragma unroll
        for (int j = 0; j < 4; ++j) o[j] = f2bf(f[j]);
        *(u16x4*)(dst + e) = o;
    } else {
        const int flat = (blockIdx.x - 9216) * 256 + threadIdx.x;
        const int lane = flat & 63;
        const int ks   = (flat >> 6) & 1;
        const int kt   = (flat >> 7) & 31;
        const int qt   = (flat >> 12) & 63;
        const int b    = flat >> 18;
        const int l31 = lane & 31, hl = lane >> 5;
        const float tA = -gwp[0] * L2E, tB = -gbp[0] * L2E;
        const float* row = SC + ((size_t)b * 2048 + qt * 32 + l31) * 2048
                              + kt * 64 + ks * 32 + 4 * hl;
        __align__(16) u16 tmp[16];
#pragma unroll
        for (int rg = 0; rg < 4; ++rg) {
            f32x4 x = *(const f32x4*)(row + rg * 8);
#pragma unroll
            for (int i = 0; i < 4; ++i) {
                float g = __builtin_amdgcn_rcpf(
                    1.0f + __builtin_amdgcn_exp2f(tA * x[i] + tB)) + 1e-8f;
                tmp[rg * 4 + i] = f2bf(__builtin_amdgcn_logf(g));  // log2
            }
        }
        u16* d = LGx + (size_t)flat * 16;
        *(uint4*)d       = *(uint4*)tmp;
        *(uint4*)(d + 8) = *(uint4*)(tmp + 8);
    }
}

// ---------------------------------------------------------------------------
// GEMM core, double-buffered (R7, unchanged): C[128x128]=A[128x512]*B^T.
// ---------------------------------------------------------------------------
__device__ __forceinline__ void gemm_core(
    const u16* __restrict__ A, const u16* __restrict__ Bw,
    int m0, int n0, u16* As, u16* Bs, f32x4 acc[4][4])
{
    const int tid = threadIdx.x;
    const int lane = tid & 63, w = tid >> 6;
    const int wm = w >> 1, wn = w & 1;
    const int l16 = lane & 15, quad = lane >> 4;
    const int srow = (lane >> 2), sch = (lane & 3) * 8;
    const f32x4 vzero = {0.f, 0.f, 0.f, 0.f};
#pragma unroll
    for (int i = 0; i < 4; ++i)
#pragma unroll
        for (int j = 0; j < 4; ++j) acc[i][j] = vzero;

#pragma unroll
    for (int j = 0; j < 2; ++j) {
        int row = w * 32 + j * 16 + srow;
        gl2lds16(&A[(size_t)(m0 + row) * 512 + sch], &As[w * 1024 + j * 512]);
        gl2lds16(&Bw[(size_t)(n0 + row) * 512 + sch], &Bs[w * 1024 + j * 512]);
    }
    for (int kt = 0; kt < 16; ++kt) {
        __syncthreads();
        const int cur = (kt & 1) * 4096;
        if (kt < 15) {
            const int nxt = ((kt + 1) & 1) * 4096;
#pragma unroll
            for (int j = 0; j < 2; ++j) {
                int row = w * 32 + j * 16 + srow;
                gl2lds16(&A[(size_t)(m0 + row) * 512 + (kt + 1) * 32 + sch],
                         &As[nxt + w * 1024 + j * 512]);
                gl2lds16(&Bw[(size_t)(n0 + row) * 512 + (kt + 1) * 32 + sch],
                         &Bs[nxt + w * 1024 + j * 512]);
            }
        }
        s16x8 af[4], bfr[4];
#pragma unroll
        for (int mt = 0; mt < 4; ++mt)
            af[mt] = *(const s16x8*)&As[cur + (wm * 64 + mt * 16 + l16) * 32 + quad * 8];
#pragma unroll
        for (int nt = 0; nt < 4; ++nt)
            bfr[nt] = *(const s16x8*)&Bs[cur + (wn * 64 + nt * 16 + l16) * 32 + quad * 8];
#pragma unroll
        for (int mt = 0; mt < 4; ++mt)
#pragma unroll
            for (int nt = 0; nt < 4; ++nt)
                acc[mt][nt] = __builtin_amdgcn_mfma_f32_16x16x32_bf16(
                    af[mt], bfr[nt], acc[mt][nt], 0, 0, 0);
    }
}

// ---------------------------------------------------------------------------
// QKV projection; epilogues emit FRAGMENT-MAJOR layouts for the attn kernel:
//  Qh: (((bh*64+qt)*4+dd)*64 + 32*hl+q31)*8 + j      (B-frag, q=lane&31)
//  Kh: (((bh*32+kt)*8+ks*4+dd)*64 + 32*hl+k31)*8 + j (A-frag, key=lane&31)
//  Vh: (((bh*32+kt)*8+ds*4+kk)*64 + 32*hl+d31)*8 + j (B-frag, d=lane&31)
// ---------------------------------------------------------------------------
__global__ __launch_bounds__(256) void proj_kernel(
    const u16* __restrict__ cQin, const u16* __restrict__ cKV,
    const u16* __restrict__ cW,
    const float* __restrict__ bq, const float* __restrict__ bk,
    const float* __restrict__ bv,
    u16* __restrict__ Qh, u16* __restrict__ Kh, u16* __restrict__ Vh)
{
    __shared__ __align__(16) u16 As[2 * 4096];
    __shared__ __align__(16) u16 Bs[2 * 4096];
    const int job = blockIdx.z;
    const u16* A = (job == 0) ? cQin : cKV;
    const u16* W = cW + (size_t)job * 262144;
    const float* bias = (job == 0) ? bq : (job == 1 ? bk : bv);
    const int m0 = blockIdx.y * 128, n0 = blockIdx.x * 128;
    f32x4 acc[4][4];
    gemm_core(A, W, m0, n0, As, Bs, acc);

    const int tid = threadIdx.x, lane = tid & 63, w = tid >> 6;
    const int wm = w >> 1, wn = w & 1, l16 = lane & 15, quad = lane >> 4;
#pragma unroll
    for (int nt = 0; nt < 4; ++nt) {
        int feat = n0 + wn * 64 + nt * 16 + l16;
        float bj = bias[feat];
        int h = feat >> 6, d = feat & 63;
#pragma unroll
        for (int mt = 0; mt < 4; ++mt) {
            int token = m0 + wm * 64 + mt * 16 + quad * 4;
            int bb = token >> 11, nn = token & 2047;
            int bh = bb * 8 + h;
            if (job == 2) {
                // V: token -> (kt,kk,hl2,jj), d -> (ds,d31); reg = jj+0..3
                int kt = nn >> 6, kk = (nn >> 4) & 3;
                int hl2 = (nn >> 3) & 1, jj = nn & 7;
                int ds = d >> 5, d31 = d & 31;
                size_t idx = ((((size_t)bh * 32 + kt) * 8 + ds * 4 + kk) * 64 +
                              32 * hl2 + d31) * 8 + jj;
                u16x4 pv;
#pragma unroll
                for (int reg = 0; reg < 4; ++reg) pv[reg] = f2bf(acc[mt][nt][reg] + bj);
                *(u16x4*)&Vh[idx] = pv;
            } else if (job == 0) {
                int dd = d >> 4, hl = (d >> 3) & 1, j = d & 7;
#pragma unroll
                for (int reg = 0; reg < 4; ++reg) {
                    int q = nn + reg;
                    size_t idx = ((((size_t)bh * 64 + (q >> 5)) * 4 + dd) * 64 +
                                  32 * hl + (q & 31)) * 8 + j;
                    Qh[idx] = f2bf((acc[mt][nt][reg] + bj) * QSCALE);
                }
            } else {
                int dd = d >> 4, hl = (d >> 3) & 1, j = d & 7;
#pragma unroll
                for (int reg = 0; reg < 4; ++reg) {
                    int key = nn + reg;
                    size_t idx = ((((size_t)bh * 32 + (key >> 6)) * 8 +
                                   ((key >> 5) & 1) * 4 + dd) * 64 +
                                  32 * hl + (key & 31)) * 8 + j;
                    Kh[idx] = f2bf(acc[mt][nt][reg] + bj);
                }
            }
        }
    }
}

// ---------------------------------------------------------------------------
// Attention, 32x32x16 MFMA. Block = 512 thr = 8 waves = (1 head, 256 q);
// wave = 32 q. Grid (8,8,4)=256. K/V tiles arrive fragment-major (pure linear
// global_load_lds copy, 1 call/wave/tensor/iter), all LDS reads are
// lane-contiguous b128 (conflict-free). P: C-layout -> A-layout via wave-
// private LDS (truncation-packed b64 writes). Row-sums via ones-MFMA.
// ---------------------------------------------------------------------------
__global__ __launch_bounds__(512) void attn_kernel(
    const u16* __restrict__ Qh, const u16* __restrict__ Kh,
    const u16* __restrict__ Vh, const u16* __restrict__ LGx,
    u16* __restrict__ Ob)
{
    __shared__ __align__(16) u16 Ks[2][4096];
    __shared__ __align__(16) u16 Vs[2][4096];
    __shared__ __align__(16) u16 Pl[8 * 2048];
    const int tid = threadIdx.x;
    const int w = tid >> 6, lane = tid & 63;
    const int l31 = lane & 31, hl = lane >> 5;
    const int b = blockIdx.z, head = blockIdx.y, qg = blockIdx.x;
    const int bh = b * 8 + head;
    const int qt = qg * 8 + w, q0 = qt * 32;
    const u16* Qp = Qh + ((size_t)bh * 64 + qt) * 2048;
    const u16* Kbase = Kh + (size_t)bh * 131072;
    const u16* Vbase = Vh + (size_t)bh * 131072;
    const u16* LGt = LGx + (((size_t)(b * 64 + qt)) * 64) * 1024;  // +(kt*2+ks)*1024
    const s16x8 ones = {0x3F80, 0x3F80, 0x3F80, 0x3F80,
                        0x3F80, 0x3F80, 0x3F80, 0x3F80};
    const f32x16 z16 = {};

    s16x8 qf[4];
#pragma unroll
    for (int dd = 0; dd < 4; ++dd)
        qf[dd] = *(const s16x8*)&Qp[dd * 512 + lane * 8];
    f32x16 o0 = z16, o1 = z16, lacc = z16;

    // prologue: stage k-tile 0 (wave w copies frag w of K and of V)
    gl2lds16(Kbase + w * 512 + lane * 8, &Ks[0][w * 512]);
    gl2lds16(Vbase + w * 512 + lane * 8, &Vs[0][w * 512]);

    for (int kt = 0; kt < 32; ++kt) {
        __syncthreads();
        const int cur = kt & 1;
        if (kt < 31) {
            const int nxt = cur ^ 1;
            gl2lds16(Kbase + (size_t)(kt + 1) * 4096 + w * 512 + lane * 8,
                     &Ks[nxt][w * 512]);
            gl2lds16(Vbase + (size_t)(kt + 1) * 4096 + w * 512 + lane * 8,
                     &Vs[nxt][w * 512]);
        }
        const u16* Kb = &Ks[cur][0];
        const u16* Vb = &Vs[cur][0];

        // S^T[key][q] = K·Q^T, two 32-key subtiles
        f32x16 st[2];
#pragma unroll
        for (int ks = 0; ks < 2; ++ks) {
            st[ks] = z16;
#pragma unroll
            for (int dd = 0; dd < 4; ++dd) {
                s16x8 kf = *(const s16x8*)&Kb[(ks * 4 + dd) * 512 + lane * 8];
                st[ks] = __builtin_amdgcn_mfma_f32_32x32x16_bf16(
                    kf, qf[dd], st[ks], 0, 0, 0);
            }
        }
        // gate + exp2 + truncation-packed P write into A-layout
#pragma unroll
        for (int ks = 0; ks < 2; ++ks) {
            __align__(16) u16 lgv[16];
            const u16* lgp = LGt + (size_t)(kt * 2 + ks) * 1024 + lane * 16;
            *(uint4*)lgv       = *(const uint4*)lgp;
            *(uint4*)(lgv + 8) = *(const uint4*)(lgp + 8);
#pragma unroll
            for (int rg = 0; rg < 4; ++rg) {
                const int r = rg * 4;
                float p0 = __builtin_amdgcn_exp2f(st[ks][r + 0] + bf2f(lgv[r + 0]));
                float p1 = __builtin_amdgcn_exp2f(st[ks][r + 1] + bf2f(lgv[r + 1]));
                float p2 = __builtin_amdgcn_exp2f(st[ks][r + 2] + bf2f(lgv[r + 2]));
                float p3 = __builtin_amdgcn_exp2f(st[ks][r + 3] + bf2f(lgv[r + 3]));
                uint2 pk = {pack_hi(p0, p1), pack_hi(p2, p3)};
                const int key0 = ks * 32 + rg * 8 + 4 * hl;   // keys key0..key0+3
                const int kk = key0 >> 4, hla = (key0 >> 3) & 1, j0 = key0 & 7;
                *(uint2*)&Pl[w * 2048 + kk * 512 + (32 * hla + l31) * 8 + j0] = pk;
            }
        }
        // PV + row-sum
#pragma unroll
        for (int kk = 0; kk < 4; ++kk) {
            s16x8 pf = *(const s16x8*)&Pl[w * 2048 + kk * 512 + lane * 8];
            lacc = __builtin_amdgcn_mfma_f32_32x32x16_bf16(pf, ones, lacc, 0, 0, 0);
            s16x8 vf0 = *(const s16x8*)&Vb[(0 * 4 + kk) * 512 + lane * 8];
            s16x8 vf1 = *(const s16x8*)&Vb[(1 * 4 + kk) * 512 + lane * 8];
            o0 = __builtin_amdgcn_mfma_f32_32x32x16_bf16(pf, vf0, o0, 0, 0, 0);
            o1 = __builtin_amdgcn_mfma_f32_32x32x16_bf16(pf, vf1, o1, 0, 0, 0);
        }
    }
    // epilogue: C-layout rows q=(reg&3)+8*(reg>>2)+4*hl; lacc rows align with o
#pragma unroll
    for (int reg = 0; reg < 16; ++reg) {
        const int qrow = (reg & 3) + 8 * (reg >> 2) + 4 * hl;
        float inv = __builtin_amdgcn_rcpf(lacc[reg]);
        size_t base = ((size_t)(b * 2048 + q0 + qrow)) * 512 + head * 64;
        Ob[base + l31]      = f2bf(o0[reg] * inv);
        Ob[base + 32 + l31] = f2bf(o1[reg] * inv);
    }
}

// ---------------------------------------------------------------------------
// Output projection: out = Ob @ Wo^T + bo, fp32 out.
// ---------------------------------------------------------------------------
__global__ __launch_bounds__(256) void out_kernel(
    const u16* __restrict__ Ob, const u16* __restrict__ cWo,
    const float* __restrict__ bo, float* __restrict__ out)
{
    __shared__ __align__(16) u16 As[2 * 4096];
    __shared__ __align__(16) u16 Bs[2 * 4096];
    const int m0 = blockIdx.y * 128, n0 = blockIdx.x * 128;
    f32x4 acc[4][4];
    gemm_core(Ob, cWo, m0, n0, As, Bs, acc);
    const int tid = threadIdx.x, lane = tid & 63, w = tid >> 6;
    const int wm = w >> 1, wn = w & 1, l16 = lane & 15, quad = lane >> 4;
#pragma unroll
    for (int nt = 0; nt < 4; ++nt) {
        int j = n0 + wn * 64 + nt * 16 + l16;
        float bj = bo[j];
#pragma unroll
        for (int mt = 0; mt < 4; ++mt) {
            int t = m0 + wm * 64 + mt * 16 + quad * 4;
#pragma unroll
            for (int reg = 0; reg < 4; ++reg)
                out[(size_t)(t + reg) * 512 + j] = acc[mt][nt][reg] + bj;
        }
    }
}

extern "C" void kernel_launch(void* const* d_in, const int* in_sizes, int n_in,
                              void* d_out, int out_size, void* d_ws, size_t ws_size,
                              hipStream_t stream)
{
    const float* Qin  = (const float*)d_in[0];
    const float* KVin = (const float*)d_in[1];
    const float* SC   = (const float*)d_in[2];
    const float* Wq   = (const float*)d_in[3];
    const float* bq   = (const float*)d_in[4];
    const float* Wk   = (const float*)d_in[5];
    const float* bk   = (const float*)d_in[6];
    const float* Wv   = (const float*)d_in[7];
    const float* bv   = (const float*)d_in[8];
    const float* gw   = (const float*)d_in[9];
    const float* gb   = (const float*)d_in[10];
    const float* Wo   = (const float*)d_in[11];
    const float* bo   = (const float*)d_in[12];
    float* out = (float*)d_out;

    u16* conv = (u16*)d_ws;
    u16* cQin = conv;
    u16* cKV  = conv + 4194304;
    u16* cW   = conv + 8388608;        // Wq,Wk,Wv,Wo each 262,144
    u16* Qh   = conv + 9437184;
    u16* Kh   = Qh + 4194304;
    u16* Vh   = Kh + 4194304;
    u16* Ob   = Vh + 4194304;
    u16* LGx  = Ob + 4194304;          // 16,777,216 u16 = 32 MiB

    hipLaunchKernelGGL(prep_kernel, dim3(13312), dim3(256), 0, stream,
                       Qin, KVin, Wq, Wk, Wv, Wo, conv, SC, gw, gb, LGx);
    hipLaunchKernelGGL(proj_kernel, dim3(4, 64, 3), dim3(256), 0, stream,
                       cQin, cKV, cW, bq, bk, bv, Qh, Kh, Vh);
    hipLaunchKernelGGL(attn_kernel, dim3(8, 8, 4), dim3(512), 0, stream,
                       Qh, Kh, Vh, LGx, Ob);
    hipLaunchKernelGGL(out_kernel, dim3(4, 64), dim3(256), 0, stream,
                       Ob, cW + 786432, bo, out);
}